// Round 3
// baseline (457.497 us; speedup 1.0000x reference)
//
#include <hip/hip_runtime.h>
#include <math.h>

// Problem constants
#define Bdim 16
#define Cdim 32
#define Ndim 207
#define CINd 64
#define COUTd 64

// strides (floats)
#define X_B (Cdim * Ndim * CINd)            // 423936
#define X_C (Ndim * CINd)                   // 13248
#define W_C (Ndim * CINd * COUTd * 2)       // 1695744
#define W_N (CINd * COUTd * 2)              // 8192

#define BN_EVAL 0.9999950000374997f

#define CHUNK_I      16
#define CHUNK_FLOATS (CHUNK_I * COUTd * 2)  // 2048 floats = 8 KB
#define NCHUNK       4

typedef float v2f __attribute__((ext_vector_type(2)));

// async global->LDS DMA, 16 B per lane; lds base must be wave-uniform
__device__ __forceinline__ void dma16(const float* g, float* lds) {
    __builtin_amdgcn_global_load_lds(
        (const __attribute__((address_space(1))) unsigned int*)g,
        (__attribute__((address_space(3))) unsigned int*)lds,
        16, 0, 0);
}

__global__ __launch_bounds__(256, 3)
void fused_multilinear(const float* __restrict__ x,
                       const float* __restrict__ rw,   // res_weight
                       const float* __restrict__ rb,   // res_bias [C*N]
                       const float* __restrict__ mw,   // mlp_w [COUT][CIN]
                       const float* __restrict__ mb,   // mlp_b [COUT]
                       const float* __restrict__ gw,   // gate_w [COUT][CIN]
                       const float* __restrict__ gb,   // gate_b [COUT]
                       const float* __restrict__ ow,   // order_w [2]
                       const float* __restrict__ obp,  // order_b [1]
                       float* __restrict__ out)
{
    // mg[i][o] = {mlp_w[o][i], gate_w[o][i]}, row stride 65 (pad: 0 conflicts, R1-proven)
    __shared__ float2 mg[64 * 65];
    // double-buffered res_weight chunk: 16 i x 64 o x 2 d, staged verbatim
    __shared__ float rwbuf[2][CHUNK_FLOATS];

    const int cn = blockIdx.x;
    const int c  = cn / Ndim;
    const int n  = cn % Ndim;
    const int o  = threadIdx.x & 63;
    const int wvid = __builtin_amdgcn_readfirstlane((int)(threadIdx.x >> 6));

    const float* wtile = rw + (size_t)c * W_C + (size_t)n * W_N;  // 32 KB contiguous
    const float* xb0   = x + (size_t)c * X_C + (size_t)(n * CINd);

    const float* xr[4];
#pragma unroll
    for (int j = 0; j < 4; ++j)
        xr[j] = xb0 + (size_t)(wvid * 4 + j) * X_B;

    // --- issue DMA for chunk 0 (each wave stages its 2 KB slice in 2 calls) ---
    {
        const float* g = wtile + wvid * 512 + o * 4;
        dma16(g,       &rwbuf[0][wvid * 512]);
        dma16(g + 256, &rwbuf[0][wvid * 512 + 256]);
    }

    // --- stage mlp_w/gate_w transposed into LDS (coalesced, drained at barrier) ---
    for (int t = threadIdx.x; t < 4096; t += 256) {
        const int oo = t >> 6;
        const int ii = t & 63;
        mg[ii * 65 + oo] = make_float2(mw[t], gw[t]);
    }
    __syncthreads();   // compiler drains vmcnt+lgkmcnt here: chunk0 + mg ready

    v2f acc01[4];   // {sum x*W0, sum x^2*W1 (BN folded later)}
    v2f accSG[4];   // {mlp, gate}
#pragma unroll
    for (int j = 0; j < 4; ++j) { acc01[j] = (v2f)(0.f); accSG[j] = (v2f)(0.f); }

    for (int cc = 0; cc < NCHUNK; ++cc) {
        const int p = cc & 1;

        // async-prefetch next chunk into the other buffer (overlaps compute)
        if (cc < NCHUNK - 1) {
            const float* g = wtile + (cc + 1) * CHUNK_FLOATS + wvid * 512 + o * 4;
            dma16(g,       &rwbuf[p ^ 1][wvid * 512]);
            dma16(g + 256, &rwbuf[p ^ 1][wvid * 512 + 256]);
        }

        // wave-uniform x chunk (scalarizes to s_load: 4 b x 16 i)
        float4 xq[4][4];
#pragma unroll
        for (int j = 0; j < 4; ++j)
#pragma unroll
            for (int q = 0; q < 4; ++q)
                xq[j][q] = *(const float4*)(xr[j] + cc * CHUNK_I + q * 4);

#pragma unroll
        for (int k = 0; k < CHUNK_I; ++k) {
            const int i = cc * CHUNK_I + k;
            const float2 w2 = *(const float2*)&rwbuf[p][k * 128 + o * 2];
            const v2f wv = { w2.x, w2.y };              // {W0, W1}
            const float2 m2 = mg[i * 65 + o];
            const v2f mv = { m2.x, m2.y };              // {mlp, gate}
#pragma unroll
            for (int j = 0; j < 4; ++j) {
                const float4 q4 = xq[j][k >> 2];
                const float xb = (k & 3) == 0 ? q4.x : (k & 3) == 1 ? q4.y
                               : (k & 3) == 2 ? q4.z : q4.w;
                const v2f xx  = { xb, xb * xb };
                acc01[j] += xx * wv;                    // v_pk_fma_f32
                const v2f xbb = { xb, xb };
                accSG[j] += xbb * mv;                   // v_pk_fma_f32
            }
        }

        __syncthreads();   // drains next-chunk DMA; protects buffer overwrite
    }

    // --- epilogue ---
    const float rbias = rb[c * Ndim + n];
    const float ow0 = ow[0], ow1 = ow[1], obias = obp[0];
    const float mbias = mb[o];
    const float gbias = gb[o];

#pragma unroll
    for (int j = 0; j < 4; ++j) {
        const int b = wvid * 4 + j;
        float uniq = (acc01[j].x + rbias) * ow0
                   + (BN_EVAL * acc01[j].y + rbias) * ow1
                   + obias;
        uniq *= 0.125f;  // SCALE/4

        const float xs = accSG[j].x + mbias;
        const float zg = accSG[j].y + gbias;
        const float g  = 1.0f / (1.0f + __expf(-zg));

        const size_t idx = (size_t)b * X_B + (size_t)c * X_C + (size_t)(n * CINd) + o;
        out[idx] = g * uniq + (1.0f - g) * xs + x[idx];
    }
}

extern "C" void kernel_launch(void* const* d_in, const int* in_sizes, int n_in,
                              void* d_out, int out_size, void* d_ws, size_t ws_size,
                              hipStream_t stream)
{
    const float* x   = (const float*)d_in[0];
    const float* rw  = (const float*)d_in[1];
    const float* rb  = (const float*)d_in[2];
    const float* mw  = (const float*)d_in[3];
    const float* mb  = (const float*)d_in[4];
    const float* gw  = (const float*)d_in[5];
    const float* gb  = (const float*)d_in[6];
    const float* ow  = (const float*)d_in[7];
    const float* ob  = (const float*)d_in[8];
    float* out = (float*)d_out;

    fused_multilinear<<<dim3(Cdim * Ndim), dim3(256), 0, stream>>>(
        x, rw, rb, mw, mb, gw, gb, ow, ob, out);
}

// Round 4
// 334.901 us; speedup vs baseline: 1.3661x; 1.3661x over previous
//
#include <hip/hip_runtime.h>

#define Bdim 16
#define Cdim 32
#define Ndim 207
#define X_B (Cdim * Ndim * 64)      // 423936
#define X_C (Ndim * 64)             // 13248
#define W_C (Ndim * 64 * 64 * 2)    // 1695744
#define W_N (64 * 64 * 2)           // 8192
#define BN_EVAL 0.9999950000374997f

using s8v = __attribute__((ext_vector_type(8))) short;
using f4v = __attribute__((ext_vector_type(4))) float;

union UV { uint4 u; s8v s; };

// pack {bf16(lo), bf16(hi)} by truncation: 1 v_perm_b32
__device__ __forceinline__ unsigned pk(float lo, float hi) {
    union { float f; unsigned u; } a, b;
    a.f = lo; b.f = hi;
    return __builtin_amdgcn_perm(b.u, a.u, 0x07060302u);
}

__global__ __launch_bounds__(256, 4)
void fused_ml_mfma(const float* __restrict__ x,
                   const float* __restrict__ rw,
                   const float* __restrict__ rb,
                   const float* __restrict__ mw,
                   const float* __restrict__ mb,
                   const float* __restrict__ gw,
                   const float* __restrict__ gb,
                   const float* __restrict__ ow,
                   const float* __restrict__ obp,
                   float* __restrict__ out)
{
    // A1[b][kappa=2i+d] = {x*ow0, x^2*BN*ow1}, row 128+8 pad
    __shared__ unsigned short A1[16 * 136];                 // 4352 B
    // A2[b][i] = bf16(x), row 64+8 pad
    __shared__ unsigned short A2[16 * 72];                  // 2304 B
    // MG[o'][i]: rows 0..63 = mlp_w, 64..127 = gate_w, row 64+8 pad
    __shared__ unsigned short MG[128 * 72];                 // 18432 B -> total 25088 B

    const int cn = blockIdx.x, c = cn / Ndim, n = cn % Ndim;
    const int t = threadIdx.x;
    const float ow0 = ow[0], ow1 = ow[1];
    const float bnow1 = ow1 * BN_EVAL;

    // ---- stage x -> A1 / A2 (coalesced: 16 threads per b-row) ----
    {
        const int b = t >> 4, i0 = (t & 15) * 4;
        const float* xrow = x + (size_t)b * X_B + (size_t)c * X_C + n * 64;
        const float4 xv = *(const float4*)(xrow + i0);
        uint4 v;
        v.x = pk(xv.x * ow0, xv.x * xv.x * bnow1);
        v.y = pk(xv.y * ow0, xv.y * xv.y * bnow1);
        v.z = pk(xv.z * ow0, xv.z * xv.z * bnow1);
        v.w = pk(xv.w * ow0, xv.w * xv.w * bnow1);
        *(uint4*)&A1[b * 136 + i0 * 2] = v;
        uint2 p;
        p.x = pk(xv.x, xv.y);
        p.y = pk(xv.z, xv.w);
        *(uint2*)&A2[b * 72 + i0] = p;
    }
    // ---- stage mlp_w/gate_w -> MG bf16 (native [o][i] layout, no transpose) ----
    {
        const int r = t >> 1, h = t & 1;   // wave-uniform branch (waves 0,1 mlp / 2,3 gate)
        const float* src = (r < 64 ? mw + r * 64 : gw + (r - 64) * 64) + h * 32;
        unsigned short* dst = &MG[r * 72 + h * 32];
#pragma unroll
        for (int u = 0; u < 4; ++u) {
            const float4 a4 = ((const float4*)src)[2 * u];
            const float4 b4 = ((const float4*)src)[2 * u + 1];
            uint4 v;
            v.x = pk(a4.x, a4.y); v.y = pk(a4.z, a4.w);
            v.z = pk(b4.x, b4.y); v.w = pk(b4.z, b4.w);
            *(uint4*)&dst[u * 8] = v;
        }
    }
    __syncthreads();

    const int l = t & 63, w = t >> 6, q = l >> 4, nn = l & 15;
    const int o = w * 16 + nn;            // this wave's o-tile column
    const float* wtile = rw + (size_t)c * W_C + (size_t)n * W_N + o * 2;

    f4v accU = {0.f, 0.f, 0.f, 0.f};
    f4v accM = {0.f, 0.f, 0.f, 0.f};
    f4v accG = {0.f, 0.f, 0.f, 0.f};

    // ---- grouped matmul: K=128 (kappa = 2i+d), B-frag straight from global ----
#pragma unroll
    for (int s = 0; s < 4; ++s) {
        const float* gp = wtile + (size_t)(16 * s + 4 * q) * 128;
        const float2 w0 = *(const float2*)(gp);
        const float2 w1 = *(const float2*)(gp + 128);
        const float2 w2 = *(const float2*)(gp + 256);
        const float2 w3 = *(const float2*)(gp + 384);
        UV bu;
        bu.u.x = pk(w0.x, w0.y); bu.u.y = pk(w1.x, w1.y);
        bu.u.z = pk(w2.x, w2.y); bu.u.w = pk(w3.x, w3.y);
        UV au; au.u = *(const uint4*)&A1[nn * 136 + 32 * s + 8 * q];
        accU = __builtin_amdgcn_mfma_f32_16x16x32_bf16(au.s, bu.s, accU, 0, 0, 0);
    }
    // ---- shared mlp+gate matmuls: K=64 ----
#pragma unroll
    for (int s = 0; s < 2; ++s) {
        UV a2u; a2u.u = *(const uint4*)&A2[nn * 72 + 32 * s + 8 * q];
        UV bm;  bm.u  = *(const uint4*)&MG[o * 72 + 32 * s + 8 * q];
        UV bg2; bg2.u = *(const uint4*)&MG[(64 + o) * 72 + 32 * s + 8 * q];
        accM = __builtin_amdgcn_mfma_f32_16x16x32_bf16(a2u.s, bm.s,  accM, 0, 0, 0);
        accG = __builtin_amdgcn_mfma_f32_16x16x32_bf16(a2u.s, bg2.s, accG, 0, 0, 0);
    }

    // ---- epilogue: D row = q*4 + reg, col = o ----
    const float rbias = rb[c * Ndim + n];
    const float uconst = rbias * (ow0 + ow1) + obp[0];
    const float mbias = mb[o], gbias = gb[o];
    const float* xcol = x + (size_t)c * X_C + n * 64 + o;
    float* ocol = out + (size_t)c * X_C + n * 64 + o;
#pragma unroll
    for (int r = 0; r < 4; ++r) {
        const int b = q * 4 + r;
        const float uniq = (accU[r] + uconst) * 0.125f;   // SCALE/4
        const float xs = accM[r] + mbias;
        const float g = 1.f / (1.f + __expf(-(accG[r] + gbias)));
        const float xres = xcol[(size_t)b * X_B];
        ocol[(size_t)b * X_B] = g * uniq + (1.f - g) * xs + xres;
    }
}

extern "C" void kernel_launch(void* const* d_in, const int* in_sizes, int n_in,
                              void* d_out, int out_size, void* d_ws, size_t ws_size,
                              hipStream_t stream)
{
    const float* x   = (const float*)d_in[0];
    const float* rw  = (const float*)d_in[1];
    const float* rb  = (const float*)d_in[2];
    const float* mw  = (const float*)d_in[3];
    const float* mb  = (const float*)d_in[4];
    const float* gw  = (const float*)d_in[5];
    const float* gb  = (const float*)d_in[6];
    const float* ow  = (const float*)d_in[7];
    const float* ob  = (const float*)d_in[8];
    float* out = (float*)d_out;

    fused_ml_mfma<<<dim3(Cdim * Ndim), dim3(256), 0, stream>>>(
        x, rw, rb, mw, mb, gw, gb, ow, ob, out);
}